// Round 9
// baseline (275.686 us; speedup 1.0000x reference)
//
#include <hip/hip_runtime.h>
#include <hip/hip_bf16.h>

typedef unsigned short u16;
typedef unsigned int   u32;
typedef __bf16 bf16x8 __attribute__((ext_vector_type(8)));
typedef float  f32x4  __attribute__((ext_vector_type(4)));

#define N_TOK 32768
constexpr long long OFF_TOKENS = 0;                       // 32768*768
constexpr long long OFF_CU     = 25165824LL;              // 33
constexpr long long OFF_COORDS = 25165857LL;              // 32768*2
constexpr long long OFF_COS    = 25231393LL;              // 32768*64
constexpr long long OFF_SIN    = 27328545LL;              // 32768*64
constexpr long long OFF_ISP    = 29425697LL;              // 32768

__device__ __forceinline__ void split_bf16(float v, u16& h, u16& l) {
    __hip_bfloat16 bh = __float2bfloat16(v);
    float fh = __bfloat162float(bh);
    __hip_bfloat16 bl = __float2bfloat16(v - fh);
    h = __builtin_bit_cast(u16, bh);
    l = __builtin_bit_cast(u16, bl);
}

__device__ __forceinline__ u32 pk2(float lo, float hi) {
    u32 a = (u32)__builtin_bit_cast(u16, __float2bfloat16(lo));
    u32 b = (u32)__builtin_bit_cast(u16, __float2bfloat16(hi));
    return a | (b << 16);
}

// ---------------------------------------------------------------------------
// prep_w: W[k][n] fp32 -> FRAGMENT-MAJOR per-(bn,kt) B tiles in workspace.
// Tile (16KB) layout: byte = wnq*4096 + hl*2048 + j*1024 + lane*16 + e*2
// holding split_hl( W[kt*32 + (lane>>4)*8 + e][bn*128 + wnq*32 + j*16 + (lane&15)] ).
// This is EXACTLY the per-lane MFMA B-operand, so the GEMM loads B with 4
// coalesced 16B global loads per lane per iter — B never touches LDS.
// ---------------------------------------------------------------------------
__global__ __launch_bounds__(256) void prep_w(const float* __restrict__ W,
                                              u16* __restrict__ wt2) {
    const int bid = blockIdx.x;           // 0..143 = bn*24 + kt
    const int bn  = bid / 24;
    const int kt  = bid - bn * 24;
    const int t   = threadIdx.x;
    #pragma unroll
    for (int p = 0; p < 2; p++) {
        const int idx  = t + p * 256;     // [wnq:2][j:1][lane:6]
        const int lane = idx & 63;
        const int j    = (idx >> 6) & 1;
        const int wnq  = idx >> 7;
        const int n    = bn * 128 + wnq * 32 + j * 16 + (lane & 15);
        const int k0   = kt * 32 + (lane >> 4) * 8;
        u16 hv[8], lv[8];
        #pragma unroll
        for (int e = 0; e < 8; e++)
            split_bf16(W[(size_t)(k0 + e) * 768 + n], hv[e], lv[e]);
        uint4 H, L;
        H.x = (u32)hv[0] | ((u32)hv[1] << 16); H.y = (u32)hv[2] | ((u32)hv[3] << 16);
        H.z = (u32)hv[4] | ((u32)hv[5] << 16); H.w = (u32)hv[6] | ((u32)hv[7] << 16);
        L.x = (u32)lv[0] | ((u32)lv[1] << 16); L.y = (u32)lv[2] | ((u32)lv[3] << 16);
        L.z = (u32)lv[4] | ((u32)lv[5] << 16); L.w = (u32)lv[6] | ((u32)lv[7] << 16);
        u16* dst = wt2 + (size_t)bid * 8192 + (((wnq << 12) | (j << 10) | (lane << 4)) >> 1);
        *(uint4*)dst          = H;
        *(uint4*)(dst + 1024) = L;        // +2048 bytes = the l-half
    }
}

// ---------------------------------------------------------------------------
// Fused patchify + 2-pass split-bf16 MFMA GEMM (math identical to rounds 5-8:
// tokens = Ah·(Bh+Bl) + bias, same accumulation order).
// BM=128 BN=128 BK=32; 512 threads = 8 waves (2M x 4N), 64x32 per wave.
// A: staged through 2 LDS buffers (transpose needs it), reg-pipelined 2 deep.
// B: DIRECT from L2-resident fragment-major tiles into MFMA operand regs —
//    no LDS traffic at all (cuts LDS bytes/iter by ~2.2x vs round 8).
// Raw s_barrier + lgkmcnt(0) only; A(t+2) global loads stay in flight across
// the barrier (issued after B(t), so the compiler's pre-MFMA wait for B is
// vmcnt(2)). XCD-chunked block swizzle (grid 1536 = 8 XCD x 192).
// ---------------------------------------------------------------------------
__global__ __launch_bounds__(512, 4) void patch_gemm_mfma(
    const float* __restrict__ img, const u16* __restrict__ wt2,
    const float* __restrict__ bias, float* __restrict__ out)
{
    __shared__ __align__(16) char smem[16384];
    char* pA0 = smem;               // Ah[128][32] bf16 (8KB each)
    char* pA1 = smem + 8192;

    // --- XCD-chunked swizzle: XCD x owns bm range [x*32, x*32+32) ---
    const int L   = blockIdx.x;           // 0..1535
    const int c   = (L & 7) * 192 + (L >> 3);
    const int bm  = c / 6;
    const int bn  = c - bm * 6;
    const int tb  = bn * 24;

    const int tid  = threadIdx.x;
    const int lane = tid & 63;
    const int wid  = tid >> 6;            // 0..7
    const int wm   = (wid >> 2) << 6;     // 0/64
    const int wn   = (wid & 3) << 5;      // 0/32/64/96
    const int lr   = lane & 15;
    const int lg   = lane >> 4;

    // A staging: thread = (row am, k-eighth aq); 8 contiguous fp32
    const int am = tid & 127;
    const int aq = tid >> 7;              // 0..3
    const int m  = bm * 128 + am;
    const int bb = m >> 10;
    const int hp = (m & 1023) >> 5;
    const int wq = m & 31;
    const float* abase = img + (size_t)bb * 786432 + (size_t)hp * 8192 + wq * 16;
    const int a_wb = am * 64 + (((aq >> 1) ^ ((am >> 3) & 1)) << 5) + ((aq & 1) << 4);

    // fragment-read byte offset (row base added per frag; row&8 == lr&8)
    const int a_rd = lr * 64 + (((lg >> 1) ^ ((lr >> 3) & 1)) << 5) + ((lg & 1) << 4);

    // B fragment base: per-(tile) + wnq*4096 + lane*16
    const char* bfrag = (const char*)wt2 + ((wid & 3) << 12) + (lane << 4);

    f32x4 acc[4][2];
    #pragma unroll
    for (int i = 0; i < 4; i++)
        #pragma unroll
        for (int j = 0; j < 2; j++) acc[i][j] = {0.f, 0.f, 0.f, 0.f};

    float4 A0a, A0b, A1a, A1b;            // 2-slot A register rotation

#define LOAD_A(ra, rb, T)                                                   \
    {   const float* ap = abase + ((T) >> 3) * 262144 +                     \
            (((T) & 7) * 2 + (aq >> 1)) * 512 + (aq & 1) * 8;               \
        ra = *(const float4*)ap;  rb = *(const float4*)(ap + 4); }

#define CVT_STORE(ra, rb, pdst)                                             \
    {   uint4 Hq;                                                           \
        Hq.x = pk2(ra.x, ra.y); Hq.y = pk2(ra.z, ra.w);                     \
        Hq.z = pk2(rb.x, rb.y); Hq.w = pk2(rb.z, rb.w);                     \
        *(uint4*)((pdst) + a_wb) = Hq; }

// iter T: load B(T) frags (issued FIRST so A-prefetch stays outstanding
// past the MFMA wait), convert/store A(T+1), prefetch A(T+2) regs,
// ds_read A frags, 16 MFMA, then lgkmcnt(0)+raw barrier (vmcnt NOT drained).
#define ITER(T, Ca, Cb, La, Lb, PACV, PAC)                                  \
    {   bf16x8 bhf[2], blf[2];                                              \
        {   const char* s = bfrag + (size_t)(tb + (T)) * 16384;             \
            bhf[0] = *(const bf16x8*)(s);                                   \
            bhf[1] = *(const bf16x8*)(s + 1024);                            \
            blf[0] = *(const bf16x8*)(s + 2048);                            \
            blf[1] = *(const bf16x8*)(s + 3072); }                          \
        if ((T) + 1 < 24) CVT_STORE(Ca, Cb, PACV);                          \
        if ((T) + 2 < 24) LOAD_A(La, Lb, (T) + 2);                          \
        bf16x8 ahf[4];                                                      \
        _Pragma("unroll")                                                   \
        for (int i = 0; i < 4; i++)                                         \
            ahf[i] = *(const bf16x8*)((PAC) + ((wm + i * 16) << 6) + a_rd); \
        _Pragma("unroll")                                                   \
        for (int i = 0; i < 4; i++)                                         \
            _Pragma("unroll")                                               \
            for (int j = 0; j < 2; j++) {                                   \
                acc[i][j] = __builtin_amdgcn_mfma_f32_16x16x32_bf16(ahf[i], bhf[j], acc[i][j], 0, 0, 0); \
                acc[i][j] = __builtin_amdgcn_mfma_f32_16x16x32_bf16(ahf[i], blf[j], acc[i][j], 0, 0, 0); \
            }                                                               \
        asm volatile("s_waitcnt lgkmcnt(0)" ::: "memory");                  \
        __builtin_amdgcn_s_barrier();                                       \
    }

    // ---- prologue: A tiles 0,1 -> regs; tile 0 -> LDS buf0 ----
    LOAD_A(A0a, A0b, 0);
    LOAD_A(A1a, A1b, 1);
    CVT_STORE(A0a, A0b, pA0);
    asm volatile("s_waitcnt lgkmcnt(0)" ::: "memory");
    __builtin_amdgcn_s_barrier();

    // ---- main loop: period-2 rotation, 24 iters ----
    #pragma unroll 1
    for (int t = 0; t < 24; t += 2) {
        ITER(t,     A1a, A1b, A0a, A0b, pA1, pA0);
        ITER(t + 1, A0a, A0b, A1a, A1b, pA0, pA1);
    }
#undef ITER
#undef LOAD_A
#undef CVT_STORE

    // ---- epilogue (C/D: col=lane&15, row=(lane>>4)*4+r) ----
    float bv[2];
    #pragma unroll
    for (int j = 0; j < 2; j++) bv[j] = bias[bn * 128 + wn + j * 16 + lr];
    #pragma unroll
    for (int i = 0; i < 4; i++) {
        const int rb = bm * 128 + wm + i * 16 + lg * 4;
        #pragma unroll
        for (int j = 0; j < 2; j++) {
            const int cg = bn * 128 + wn + j * 16 + lr;
            #pragma unroll
            for (int r = 0; r < 4; r++)
                out[OFF_TOKENS + (size_t)(rb + r) * 768 + cg] = acc[i][j][r] + bv[j];
        }
    }
}

// ---------------------------------------------------------------------------
// Side outputs: thread per (token, freq-pair); float2 stores for the repeat.
// ---------------------------------------------------------------------------
__global__ __launch_bounds__(256) void aux_kernel(float* __restrict__ out)
{
    const int idx = blockIdx.x * 256 + threadIdx.x;     // 0 .. 32768*32-1
    if (idx >= N_TOK * 32) return;
    const int n  = idx >> 5;
    const int jd = idx & 31;

    const int hp = (n & 1023) >> 5;
    const int wp = n & 31;

    const int coord = (jd < 16) ? hp : wp;
    const int j = jd & 15;
    const float freq = exp2f(-(float)j * 0.8304820237218406f);  // 10000^(-j/16)
    float s, c;
    sincosf((float)coord * freq, &s, &c);

    const long long off = (long long)n * 64 + jd * 2;
    *(float2*)(out + OFF_COS + off) = make_float2(c, c);
    *(float2*)(out + OFF_SIN + off) = make_float2(s, s);

    if (jd == 0) {
        out[OFF_COORDS + 2 * (long long)n]     = (float)hp;
        out[OFF_COORDS + 2 * (long long)n + 1] = (float)wp;
        out[OFF_ISP + n] = 1.0f;
    }
    if (jd == 1 && n < 33) {
        out[OFF_CU + n] = (float)(n * 1024);
    }
}

extern "C" void kernel_launch(void* const* d_in, const int* in_sizes, int n_in,
                              void* d_out, int out_size, void* d_ws, size_t ws_size,
                              hipStream_t stream) {
    const float* img  = (const float*)d_in[0];   // (32,3,512,512)
    const float* W    = (const float*)d_in[1];   // (768,768)
    const float* bias = (const float*)d_in[2];   // (768,)
    float* out = (float*)d_out;
    u16* wt2 = (u16*)d_ws;                       // 144 tiles * 16KB = 2.25 MB

    prep_w<<<144, 256, 0, stream>>>(W, wt2);

    patch_gemm_mfma<<<1536, 512, 0, stream>>>(img, wt2, bias, out);

    const int aux_elems = N_TOK * 32;
    aux_kernel<<<(aux_elems + 255) / 256, 256, 0, stream>>>(out);
}

// Round 12
// 268.095 us; speedup vs baseline: 1.0283x; 1.0283x over previous
//
#include <hip/hip_runtime.h>
#include <hip/hip_bf16.h>

typedef unsigned short u16;
typedef unsigned int   u32;
typedef __bf16 bf16x8 __attribute__((ext_vector_type(8)));
typedef float  f32x4  __attribute__((ext_vector_type(4)));

#define N_TOK 32768
constexpr long long OFF_TOKENS = 0;                       // 32768*768
constexpr long long OFF_CU     = 25165824LL;              // 33
constexpr long long OFF_COORDS = 25165857LL;              // 32768*2
constexpr long long OFF_COS    = 25231393LL;              // 32768*64
constexpr long long OFF_SIN    = 27328545LL;              // 32768*64
constexpr long long OFF_ISP    = 29425697LL;              // 32768

__device__ __forceinline__ void split_bf16(float v, u16& h, u16& l) {
    __hip_bfloat16 bh = __float2bfloat16(v);
    float fh = __bfloat162float(bh);
    __hip_bfloat16 bl = __float2bfloat16(v - fh);
    h = __builtin_bit_cast(u16, bh);
    l = __builtin_bit_cast(u16, bl);
}

__device__ __forceinline__ u32 pk2(float lo, float hi) {
    u32 a = (u32)__builtin_bit_cast(u16, __float2bfloat16(lo));
    u32 b = (u32)__builtin_bit_cast(u16, __float2bfloat16(hi));
    return a | (b << 16);
}

// ---------------------------------------------------------------------------
// prep_w: W[k][n] fp32 -> FRAGMENT-MAJOR per-(bn,kt) B tiles in workspace.
// Tile (16KB) layout: byte = wnq*4096 + hl*2048 + j*1024 + lane*16 + e*2
// holding split_hl( W[kt*32 + (lane>>4)*8 + e][bn*128 + wnq*32 + j*16 + (lane&15)] ).
// Exactly the per-lane MFMA B-operand -> B never touches LDS in the GEMM.
// (Verified correct by round 9's passing run.)
// ---------------------------------------------------------------------------
__global__ __launch_bounds__(256) void prep_w(const float* __restrict__ W,
                                              u16* __restrict__ wt2) {
    const int bid = blockIdx.x;           // 0..143 = bn*24 + kt
    const int bn  = bid / 24;
    const int kt  = bid - bn * 24;
    const int t   = threadIdx.x;
    #pragma unroll
    for (int p = 0; p < 2; p++) {
        const int idx  = t + p * 256;     // [wnq:2][j:1][lane:6]
        const int lane = idx & 63;
        const int j    = (idx >> 6) & 1;
        const int wnq  = idx >> 7;
        const int n    = bn * 128 + wnq * 32 + j * 16 + (lane & 15);
        const int k0   = kt * 32 + (lane >> 4) * 8;
        u16 hv[8], lv[8];
        #pragma unroll
        for (int e = 0; e < 8; e++)
            split_bf16(W[(size_t)(k0 + e) * 768 + n], hv[e], lv[e]);
        uint4 H, L;
        H.x = (u32)hv[0] | ((u32)hv[1] << 16); H.y = (u32)hv[2] | ((u32)hv[3] << 16);
        H.z = (u32)hv[4] | ((u32)hv[5] << 16); H.w = (u32)hv[6] | ((u32)hv[7] << 16);
        L.x = (u32)lv[0] | ((u32)lv[1] << 16); L.y = (u32)lv[2] | ((u32)lv[3] << 16);
        L.z = (u32)lv[4] | ((u32)lv[5] << 16); L.w = (u32)lv[6] | ((u32)lv[7] << 16);
        u16* dst = wt2 + (size_t)bid * 8192 + (((wnq << 12) | (j << 10) | (lane << 4)) >> 1);
        *(uint4*)dst          = H;
        *(uint4*)(dst + 1024) = L;        // +2048 bytes = the l-half
    }
}

// ---------------------------------------------------------------------------
// Fused patchify + 2-pass split-bf16 MFMA GEMM (math identical to rounds 5-9:
// tokens = Ah·(Bh+Bl) + bias, same accumulation order).
// BM=128 BN=128 BK=32; 512 threads = 8 waves (2M x 4N), 64x32 per wave.
// A: 2 LDS buffers in [kq:4][m:128]x16B layout -> bank-uniform writes AND
//    reads (kills the constant 7.08M SQ_LDS_BANK_CONFLICT of rounds 7-9).
// B: direct from L2-resident fragment-major tiles, REGISTER DOUBLE-BUFFERED
//    (B(t+1) issued during iter t -> full iteration of latency cover).
// Raw s_barrier + lgkmcnt(0); vmcnt never drained in-loop.
// XCD-chunked block swizzle (grid 1536 = 8 XCD x 192).
// ---------------------------------------------------------------------------
__global__ __launch_bounds__(512, 4) void patch_gemm_mfma(
    const float* __restrict__ img, const u16* __restrict__ wt2,
    const float* __restrict__ bias, float* __restrict__ out)
{
    __shared__ __align__(16) char smem[16384];
    char* pA0 = smem;               // A[kq:4][m:128] x 16B (8KB each)
    char* pA1 = smem + 8192;

    // --- XCD-chunked swizzle: XCD x owns bm range [x*32, x*32+32) ---
    const int L   = blockIdx.x;           // 0..1535
    const int c   = (L & 7) * 192 + (L >> 3);
    const int bm  = c / 6;
    const int bn  = c - bm * 6;
    const int tb  = bn * 24;

    const int tid  = threadIdx.x;
    const int lane = tid & 63;
    const int wid  = tid >> 6;            // 0..7
    const int wm   = (wid >> 2) << 6;     // 0/64
    const int wn   = (wid & 3) << 5;      // 0/32/64/96
    const int lr   = lane & 15;
    const int lg   = lane >> 4;

    // A staging: thread = (row am, k-eighth aq); 8 contiguous fp32
    const int am = tid & 127;
    const int aq = tid >> 7;              // 0..3
    const int m  = bm * 128 + am;
    const int bb = m >> 10;
    const int hp = (m & 1023) >> 5;
    const int wq = m & 31;
    const float* abase = img + (size_t)bb * 786432 + (size_t)hp * 8192 + wq * 16;
    const int a_wb = aq * 2048 + am * 16;             // bank-uniform write

    // fragment-read byte offset: + (wm + i*16)*16 added per frag
    const int a_rd = lg * 2048 + lr * 16;             // bank-uniform read

    // B fragment base: per-(tile) + wnq*4096 + lane*16
    const char* bfrag = (const char*)wt2 + ((wid & 3) << 12) + (lane << 4);

    f32x4 acc[4][2];
    #pragma unroll
    for (int i = 0; i < 4; i++)
        #pragma unroll
        for (int j = 0; j < 2; j++) acc[i][j] = {0.f, 0.f, 0.f, 0.f};

    float4 A0a, A0b, A1a, A1b;            // 2-slot A register rotation
    bf16x8 B0[4], B1[4];                  // 2-slot B fragment rotation
                                          // [0]=h j0, [1]=h j1, [2]=l j0, [3]=l j1

#define LOAD_A(ra, rb, T)                                                   \
    {   const float* ap = abase + ((T) >> 3) * 262144 +                     \
            (((T) & 7) * 2 + (aq >> 1)) * 512 + (aq & 1) * 8;               \
        ra = *(const float4*)ap;  rb = *(const float4*)(ap + 4); }

#define CVT_STORE(ra, rb, pdst)                                             \
    {   uint4 Hq;                                                           \
        Hq.x = pk2(ra.x, ra.y); Hq.y = pk2(ra.z, ra.w);                     \
        Hq.z = pk2(rb.x, rb.y); Hq.w = pk2(rb.z, rb.w);                     \
        *(uint4*)((pdst) + a_wb) = Hq; }

#define BLOAD(T, Bv)                                                        \
    {   const char* s = bfrag + (size_t)(tb + (T)) * 16384;                 \
        Bv[0] = *(const bf16x8*)(s);                                        \
        Bv[1] = *(const bf16x8*)(s + 1024);                                 \
        Bv[2] = *(const bf16x8*)(s + 2048);                                 \
        Bv[3] = *(const bf16x8*)(s + 3072); }

#define COMPUTE(PAC, Bv)                                                    \
    {   bf16x8 ahf[4];                                                      \
        _Pragma("unroll")                                                   \
        for (int i = 0; i < 4; i++)                                         \
            ahf[i] = *(const bf16x8*)((PAC) + ((wm + i * 16) << 4) + a_rd); \
        _Pragma("unroll")                                                   \
        for (int i = 0; i < 4; i++)                                         \
            _Pragma("unroll")                                               \
            for (int j = 0; j < 2; j++) {                                   \
                acc[i][j] = __builtin_amdgcn_mfma_f32_16x16x32_bf16(ahf[i], Bv[j],     acc[i][j], 0, 0, 0); \
                acc[i][j] = __builtin_amdgcn_mfma_f32_16x16x32_bf16(ahf[i], Bv[j + 2], acc[i][j], 0, 0, 0); \
            } }

// iter T: prefetch B(T+1) regs, stage A(T+1) LDS, prefetch A(T+2) regs,
//         ds_read A frags, 16 MFMA on B(T) set, lgkmcnt(0)+raw barrier.
#define ITER(T, Ca, Cb, La, Lb, PACV, PAC, Bnx, Bcur)                       \
    {   if ((T) + 1 < 24) BLOAD((T) + 1, Bnx);                              \
        if ((T) + 1 < 24) CVT_STORE(Ca, Cb, PACV);                          \
        if ((T) + 2 < 24) LOAD_A(La, Lb, (T) + 2);                          \
        COMPUTE(PAC, Bcur);                                                 \
        asm volatile("s_waitcnt lgkmcnt(0)" ::: "memory");                  \
        __builtin_amdgcn_s_barrier();                                       \
    }

    // ---- prologue: A tiles 0,1 -> regs; B tile 0 -> regs; A0 -> LDS ----
    LOAD_A(A0a, A0b, 0);
    LOAD_A(A1a, A1b, 1);
    BLOAD(0, B0);
    CVT_STORE(A0a, A0b, pA0);
    asm volatile("s_waitcnt lgkmcnt(0)" ::: "memory");
    __builtin_amdgcn_s_barrier();

    // ---- main loop: period-2 rotation, 24 iters ----
    #pragma unroll 1
    for (int t = 0; t < 24; t += 2) {
        ITER(t,     A1a, A1b, A0a, A0b, pA1, pA0, B1, B0);
        ITER(t + 1, A0a, A0b, A1a, A1b, pA0, pA1, B0, B1);
    }
#undef ITER
#undef LOAD_A
#undef CVT_STORE
#undef BLOAD
#undef COMPUTE

    // ---- epilogue (C/D: col=lane&15, row=(lane>>4)*4+r) ----
    float bv[2];
    #pragma unroll
    for (int j = 0; j < 2; j++) bv[j] = bias[bn * 128 + wn + j * 16 + lr];
    #pragma unroll
    for (int i = 0; i < 4; i++) {
        const int rb = bm * 128 + wm + i * 16 + lg * 4;
        #pragma unroll
        for (int j = 0; j < 2; j++) {
            const int cg = bn * 128 + wn + j * 16 + lr;
            #pragma unroll
            for (int r = 0; r < 4; r++)
                out[OFF_TOKENS + (size_t)(rb + r) * 768 + cg] = acc[i][j][r] + bv[j];
        }
    }
}

// ---------------------------------------------------------------------------
// Side outputs: thread per (token, freq-pair); float2 stores for the repeat.
// ---------------------------------------------------------------------------
__global__ __launch_bounds__(256) void aux_kernel(float* __restrict__ out)
{
    const int idx = blockIdx.x * 256 + threadIdx.x;     // 0 .. 32768*32-1
    if (idx >= N_TOK * 32) return;
    const int n  = idx >> 5;
    const int jd = idx & 31;

    const int hp = (n & 1023) >> 5;
    const int wp = n & 31;

    const int coord = (jd < 16) ? hp : wp;
    const int j = jd & 15;
    const float freq = exp2f(-(float)j * 0.8304820237218406f);  // 10000^(-j/16)
    float s, c;
    sincosf((float)coord * freq, &s, &c);

    const long long off = (long long)n * 64 + jd * 2;
    *(float2*)(out + OFF_COS + off) = make_float2(c, c);
    *(float2*)(out + OFF_SIN + off) = make_float2(s, s);

    if (jd == 0) {
        out[OFF_COORDS + 2 * (long long)n]     = (float)hp;
        out[OFF_COORDS + 2 * (long long)n + 1] = (float)wp;
        out[OFF_ISP + n] = 1.0f;
    }
    if (jd == 1 && n < 33) {
        out[OFF_CU + n] = (float)(n * 1024);
    }
}

extern "C" void kernel_launch(void* const* d_in, const int* in_sizes, int n_in,
                              void* d_out, int out_size, void* d_ws, size_t ws_size,
                              hipStream_t stream) {
    const float* img  = (const float*)d_in[0];   // (32,3,512,512)
    const float* W    = (const float*)d_in[1];   // (768,768)
    const float* bias = (const float*)d_in[2];   // (768,)
    float* out = (float*)d_out;
    u16* wt2 = (u16*)d_ws;                       // 144 tiles * 16KB = 2.25 MB

    prep_w<<<144, 256, 0, stream>>>(W, wt2);

    patch_gemm_mfma<<<1536, 512, 0, stream>>>(img, wt2, bias, out);

    const int aux_elems = N_TOK * 32;
    aux_kernel<<<(aux_elems + 255) / 256, 256, 0, stream>>>(out);
}

// Round 13
// 255.964 us; speedup vs baseline: 1.0770x; 1.0474x over previous
//
#include <hip/hip_runtime.h>
#include <hip/hip_bf16.h>

typedef unsigned short u16;
typedef unsigned int   u32;
typedef __bf16 bf16x8 __attribute__((ext_vector_type(8)));
typedef float  f32x4  __attribute__((ext_vector_type(4)));

#define N_TOK 32768
constexpr long long OFF_TOKENS = 0;                       // 32768*768
constexpr long long OFF_CU     = 25165824LL;              // 33
constexpr long long OFF_COORDS = 25165857LL;              // 32768*2
constexpr long long OFF_COS    = 25231393LL;              // 32768*64
constexpr long long OFF_SIN    = 27328545LL;              // 32768*64
constexpr long long OFF_ISP    = 29425697LL;              // 32768

__device__ __forceinline__ void split_bf16(float v, u16& h, u16& l) {
    __hip_bfloat16 bh = __float2bfloat16(v);
    float fh = __bfloat162float(bh);
    __hip_bfloat16 bl = __float2bfloat16(v - fh);
    h = __builtin_bit_cast(u16, bh);
    l = __builtin_bit_cast(u16, bl);
}

__device__ __forceinline__ u32 pk2(float lo, float hi) {
    u32 a = (u32)__builtin_bit_cast(u16, __float2bfloat16(lo));
    u32 b = (u32)__builtin_bit_cast(u16, __float2bfloat16(hi));
    return a | (b << 16);
}

// ---------------------------------------------------------------------------
// prep_w: W[k][n] fp32 -> FRAGMENT-MAJOR per-(bn,kt) B tiles in workspace.
// Tile (16KB): byte = wnq*4096 + hl*2048 + j*1024 + lane*16 + e*2 holding
// split_hl( W[kt*32 + (lane>>4)*8 + e][bn*128 + wnq*32 + j*16 + (lane&15)] ).
// = exact per-lane MFMA B-operands; ALSO the exact LDS image for linear
// global_load_lds staging (LDS reads then hit 8 touches/bank: conflict-free).
// (Layout verified correct by rounds 9/12 passing runs.)
// ---------------------------------------------------------------------------
__global__ __launch_bounds__(256) void prep_w(const float* __restrict__ W,
                                              u16* __restrict__ wt2) {
    const int bid = blockIdx.x;           // 0..143 = bn*24 + kt
    const int bn  = bid / 24;
    const int kt  = bid - bn * 24;
    const int t   = threadIdx.x;
    #pragma unroll
    for (int p = 0; p < 2; p++) {
        const int idx  = t + p * 256;     // [wnq:2][j:1][lane:6]
        const int lane = idx & 63;
        const int j    = (idx >> 6) & 1;
        const int wnq  = idx >> 7;
        const int n    = bn * 128 + wnq * 32 + j * 16 + (lane & 15);
        const int k0   = kt * 32 + (lane >> 4) * 8;
        u16 hv[8], lv[8];
        #pragma unroll
        for (int e = 0; e < 8; e++)
            split_bf16(W[(size_t)(k0 + e) * 768 + n], hv[e], lv[e]);
        uint4 H, L;
        H.x = (u32)hv[0] | ((u32)hv[1] << 16); H.y = (u32)hv[2] | ((u32)hv[3] << 16);
        H.z = (u32)hv[4] | ((u32)hv[5] << 16); H.w = (u32)hv[6] | ((u32)hv[7] << 16);
        L.x = (u32)lv[0] | ((u32)lv[1] << 16); L.y = (u32)lv[2] | ((u32)lv[3] << 16);
        L.z = (u32)lv[4] | ((u32)lv[5] << 16); L.w = (u32)lv[6] | ((u32)lv[7] << 16);
        u16* dst = wt2 + (size_t)bid * 8192 + (((wnq << 12) | (j << 10) | (lane << 4)) >> 1);
        *(uint4*)dst          = H;
        *(uint4*)(dst + 1024) = L;        // +2048 bytes = the l-half
    }
}

// ---------------------------------------------------------------------------
// Fused patchify + 2-pass split-bf16 MFMA GEMM (math identical to rounds 5-12).
// BM=128 BN=128 BK=32; 512 threads = 8 waves (2M x 4N), 64x32 per wave.
// A: 2 LDS buffers, [kq:4][m:128]x16B bank-uniform layout (r12: conflicts=0),
//    reg-staged 2-deep (LOAD_A(t+2) crosses the barrier in flight).
// B: staged ONCE per block-iter (16KB) via global_load_lds into 2 LDS buffers
//    from the fragment-major tiles (r12 fetched B twice/iter from L2 with no
//    reuse: 1.13GB L2 traffic = the bottleneck; this halves VMEM/blk-iter).
// Pre-barrier wait: s_waitcnt vmcnt(2) lgkmcnt(0) — drains GLOADB(t+1)
// (needed next iter) + older, keeps LOAD_A(t+2) in flight. Last two iters
// peeled with vmcnt(0) (no LOAD_A outstanding there -> count must shrink).
// XCD-chunked block swizzle (grid 1536 = 8 XCD x 192).
// ---------------------------------------------------------------------------
__global__ __launch_bounds__(512, 4) void patch_gemm_mfma(
    const float* __restrict__ img, const u16* __restrict__ wt2,
    const float* __restrict__ bias, float* __restrict__ out)
{
    __shared__ __align__(16) char smem[49152];
    char* pA0 = smem;               // A[kq:4][m:128] x 16B (8KB each)
    char* pA1 = smem + 8192;
    char* pB0 = smem + 16384;       // fragment-major B image (16KB each)
    char* pB1 = smem + 32768;

    // --- XCD-chunked swizzle: XCD x owns bm range [x*32, x*32+32) ---
    const int L   = blockIdx.x;           // 0..1535
    const int c   = (L & 7) * 192 + (L >> 3);
    const int bm  = c / 6;
    const int bn  = c - bm * 6;
    const int tb  = bn * 24;

    const int tid  = threadIdx.x;
    const int lane = tid & 63;
    const int wid  = tid >> 6;            // 0..7
    const int wm   = (wid >> 2) << 6;     // 0/64
    const int wn   = (wid & 3) << 5;      // 0/32/64/96
    const int lr   = lane & 15;
    const int lg   = lane >> 4;

    // A staging: thread = (row am, k-eighth aq); 8 contiguous fp32
    const int am = tid & 127;
    const int aq = tid >> 7;              // 0..3
    const int m  = bm * 128 + am;
    const int bb = m >> 10;
    const int hp = (m & 1023) >> 5;
    const int wq = m & 31;
    const float* abase = img + (size_t)bb * 786432 + (size_t)hp * 8192 + wq * 16;
    const int a_wb = aq * 2048 + am * 16;             // bank-uniform write

    // A fragment-read byte offset: + (wm + i*16)*16 added per frag
    const int a_rd = lg * 2048 + lr * 16;             // bank-uniform read

    // B fragment-read byte offset within a B buffer: + j*1024 / +2048 (l)
    const int b_rd = ((wid & 3) << 12) + (lane << 4); // bank-uniform read

    f32x4 acc[4][2];
    #pragma unroll
    for (int i = 0; i < 4; i++)
        #pragma unroll
        for (int j = 0; j < 2; j++) acc[i][j] = {0.f, 0.f, 0.f, 0.f};

    float4 A0a, A0b, A1a, A1b;            // 2-slot A register rotation

#define LOAD_A(ra, rb, T)                                                   \
    {   const float* ap = abase + ((T) >> 3) * 262144 +                     \
            (((T) & 7) * 2 + (aq >> 1)) * 512 + (aq & 1) * 8;               \
        ra = *(const float4*)ap;  rb = *(const float4*)(ap + 4); }

#define CVT_STORE(ra, rb, pdst)                                             \
    {   uint4 Hq;                                                           \
        Hq.x = pk2(ra.x, ra.y); Hq.y = pk2(ra.z, ra.w);                     \
        Hq.z = pk2(rb.x, rb.y); Hq.w = pk2(rb.z, rb.w);                     \
        *(uint4*)((pdst) + a_wb) = Hq; }

#define GLOADB(T, dst)                                                      \
    {   const char* s = (const char*)wt2 + (size_t)(tb + (T)) * 16384       \
                        + (wid << 11) + (lane << 4);                        \
        char* d = (dst) + (wid << 11);                                      \
        __builtin_amdgcn_global_load_lds(                                   \
            (const __attribute__((address_space(1))) u32*)s,                \
            (__attribute__((address_space(3))) u32*)(d + (lane << 4)), 16, 0, 0); \
        __builtin_amdgcn_global_load_lds(                                   \
            (const __attribute__((address_space(1))) u32*)(s + 1024),       \
            (__attribute__((address_space(3))) u32*)(d + 1024 + (lane << 4)), 16, 0, 0); }

#define COMPUTE(PAC, PBC)                                                   \
    {   bf16x8 ahf[4], bhf[2], blf[2];                                      \
        _Pragma("unroll")                                                   \
        for (int j = 0; j < 2; j++) {                                       \
            bhf[j] = *(const bf16x8*)((PBC) + b_rd + (j << 10));            \
            blf[j] = *(const bf16x8*)((PBC) + b_rd + (j << 10) + 2048);     \
        }                                                                   \
        _Pragma("unroll")                                                   \
        for (int i = 0; i < 4; i++)                                         \
            ahf[i] = *(const bf16x8*)((PAC) + ((wm + i * 16) << 4) + a_rd); \
        _Pragma("unroll")                                                   \
        for (int i = 0; i < 4; i++)                                         \
            _Pragma("unroll")                                               \
            for (int j = 0; j < 2; j++) {                                   \
                acc[i][j] = __builtin_amdgcn_mfma_f32_16x16x32_bf16(ahf[i], bhf[j], acc[i][j], 0, 0, 0); \
                acc[i][j] = __builtin_amdgcn_mfma_f32_16x16x32_bf16(ahf[i], blf[j], acc[i][j], 0, 0, 0); \
            } }

// iter T: DMA B(T+1), prefetch A(T+2) regs, CVT/store A(T+1) [compiler
// inserts vmcnt(4) here: waits LOAD_A(T+1) only], COMPUTE(T), then
// WAITSTR+lgkmcnt(0) + raw barrier.
#define ITER(T, WAITSTR, Ca, Cb, La, Lb, PACV, PAC, PBG, PBC)               \
    {   if ((T) + 1 < 24) GLOADB((T) + 1, PBG);                             \
        if ((T) + 2 < 24) LOAD_A(La, Lb, (T) + 2);                          \
        if ((T) + 1 < 24) CVT_STORE(Ca, Cb, PACV);                          \
        COMPUTE(PAC, PBC);                                                  \
        asm volatile("s_waitcnt " WAITSTR " lgkmcnt(0)" ::: "memory");      \
        __builtin_amdgcn_s_barrier();                                       \
    }

    // ---- prologue: B(0) DMA; A(0),A(1) regs; A(0)->LDS; drain; barrier ----
    GLOADB(0, pB0);
    LOAD_A(A0a, A0b, 0);
    LOAD_A(A1a, A1b, 1);
    CVT_STORE(A0a, A0b, pA0);   // waits LOAD_A(0) -> drains GLOADB(0) too
    asm volatile("s_waitcnt vmcnt(2) lgkmcnt(0)" ::: "memory");  // keep A(1)
    __builtin_amdgcn_s_barrier();

    // ---- main loop: 22 iters in-loop (vmcnt(2)), last 2 peeled (vmcnt(0)) --
    #pragma unroll 1
    for (int t = 0; t < 22; t += 2) {
        ITER(t,     "vmcnt(2)", A1a, A1b, A0a, A0b, pA1, pA0, pB1, pB0);
        ITER(t + 1, "vmcnt(2)", A0a, A0b, A1a, A1b, pA0, pA1, pB0, pB1);
    }
    ITER(22, "vmcnt(0)", A1a, A1b, A0a, A0b, pA1, pA0, pB1, pB0);
    ITER(23, "vmcnt(0)", A0a, A0b, A1a, A1b, pA0, pA1, pB0, pB1);
#undef ITER
#undef LOAD_A
#undef CVT_STORE
#undef GLOADB
#undef COMPUTE

    // ---- epilogue (C/D: col=lane&15, row=(lane>>4)*4+r) ----
    float bv[2];
    #pragma unroll
    for (int j = 0; j < 2; j++) bv[j] = bias[bn * 128 + wn + j * 16 + lr];
    #pragma unroll
    for (int i = 0; i < 4; i++) {
        const int rb = bm * 128 + wm + i * 16 + lg * 4;
        #pragma unroll
        for (int j = 0; j < 2; j++) {
            const int cg = bn * 128 + wn + j * 16 + lr;
            #pragma unroll
            for (int r = 0; r < 4; r++)
                out[OFF_TOKENS + (size_t)(rb + r) * 768 + cg] = acc[i][j][r] + bv[j];
        }
    }
}

// ---------------------------------------------------------------------------
// Side outputs: thread per (token, freq-pair); float2 stores for the repeat.
// ---------------------------------------------------------------------------
__global__ __launch_bounds__(256) void aux_kernel(float* __restrict__ out)
{
    const int idx = blockIdx.x * 256 + threadIdx.x;     // 0 .. 32768*32-1
    if (idx >= N_TOK * 32) return;
    const int n  = idx >> 5;
    const int jd = idx & 31;

    const int hp = (n & 1023) >> 5;
    const int wp = n & 31;

    const int coord = (jd < 16) ? hp : wp;
    const int j = jd & 15;
    const float freq = exp2f(-(float)j * 0.8304820237218406f);  // 10000^(-j/16)
    float s, c;
    sincosf((float)coord * freq, &s, &c);

    const long long off = (long long)n * 64 + jd * 2;
    *(float2*)(out + OFF_COS + off) = make_float2(c, c);
    *(float2*)(out + OFF_SIN + off) = make_float2(s, s);

    if (jd == 0) {
        out[OFF_COORDS + 2 * (long long)n]     = (float)hp;
        out[OFF_COORDS + 2 * (long long)n + 1] = (float)wp;
        out[OFF_ISP + n] = 1.0f;
    }
    if (jd == 1 && n < 33) {
        out[OFF_CU + n] = (float)(n * 1024);
    }
}

extern "C" void kernel_launch(void* const* d_in, const int* in_sizes, int n_in,
                              void* d_out, int out_size, void* d_ws, size_t ws_size,
                              hipStream_t stream) {
    const float* img  = (const float*)d_in[0];   // (32,3,512,512)
    const float* W    = (const float*)d_in[1];   // (768,768)
    const float* bias = (const float*)d_in[2];   // (768,)
    float* out = (float*)d_out;
    u16* wt2 = (u16*)d_ws;                       // 144 tiles * 16KB = 2.25 MB

    prep_w<<<144, 256, 0, stream>>>(W, wt2);

    patch_gemm_mfma<<<1536, 512, 0, stream>>>(img, wt2, bias, out);

    const int aux_elems = N_TOK * 32;
    aux_kernel<<<(aux_elems + 255) / 256, 256, 0, stream>>>(out);
}